// Round 1
// baseline (1092.557 us; speedup 1.0000x reference)
//
#include <hip/hip_runtime.h>

typedef unsigned long long u64;
typedef unsigned int u32;

#define FEAT 52
#define NPIX 2704          // 52*52
#define NANC 24336         // NPIX*9
#define PRE  12000
#define POST 2000
#define NSORT 32768
#define ROWW 192           // u64 words per mask row (12288 bits = 24 chunks * 512)

// ---- d_out layout (float elements) ----
#define ROIS_OFF 0
#define LOCS_OFF 8000
#define CLS_OFF  105344
#define OBJ_OFF  154016
#define CLS2_OFF 178352

// ---- ws layout (byte offsets) ----
#define OFF_X64   0ull          //  692224 f64
#define OFF_H64   5537792ull    //  692224 f64
#define OFF_REG64 11075584ull   //   97344 f64
#define OFF_SC64  11854336ull   //   24336 f64
#define OFF_ROI64 12049024ull   //   97344 f64
#define OFF_KEYS  12827776ull   //   32768 u64
#define OFF_SBOX  13089920ull   //   49152 f64
#define OFF_SAREA 13483136ull   //   12288 f64
#define OFF_SUPP  13581440ull   //     192 u64
#define OFF_MASK  13582976ull   //   12000*192 u64 = 18432000 B  (end ~32.0 MB)

// ---------------------------------------------------------------- prep: x -> f64
__global__ __launch_bounds__(256) void k_prep(const float* __restrict__ x,
                                              double* __restrict__ x64) {
    int t = blockIdx.x * 256 + threadIdx.x;   // grid 2704 -> exactly 692224
    x64[t] = (double)x[t];
}

// ---------------------------------------------------------------- conv 3x3 256->256 (f64)
__global__ __launch_bounds__(256) void k_conv3(const double* __restrict__ x64,
                                               const float* __restrict__ w,
                                               const float* __restrict__ b,
                                               double* __restrict__ h64) {
    __shared__ double wsh[9216];              // 4 oc * 256 ci * 9 taps = 72 KiB
    const int o0 = blockIdx.y * 4;
    for (int t = threadIdx.x; t < 9216; t += 256)
        wsh[t] = (double)w[o0 * 2304 + t];    // layout [oo][ci][k]
    __syncthreads();
    int p = blockIdx.x * 256 + threadIdx.x;
    if (p >= NPIX) return;
    int y = p / FEAT, xq = p % FEAT;
    double a0 = (double)b[o0+0], a1 = (double)b[o0+1];
    double a2 = (double)b[o0+2], a3 = (double)b[o0+3];
    int offs[9]; bool vm[9];
    #pragma unroll
    for (int kh = 0; kh < 3; ++kh) {
        #pragma unroll
        for (int kw = 0; kw < 3; ++kw) {
            int iy = y + kh - 1, ix = xq + kw - 1;
            bool v = ((unsigned)iy < (unsigned)FEAT) && ((unsigned)ix < (unsigned)FEAT);
            vm[kh*3+kw] = v;
            offs[kh*3+kw] = v ? iy*FEAT + ix : 0;
        }
    }
    for (int ci = 0; ci < 256; ++ci) {
        const double* xb = x64 + ci * NPIX;
        double xv[9];
        #pragma unroll
        for (int k = 0; k < 9; ++k) { double t = xb[offs[k]]; xv[k] = vm[k] ? t : 0.0; }
        const double* wr = wsh + ci * 9;
        #pragma unroll
        for (int k = 0; k < 9; ++k) {
            a0 += xv[k] * wr[k];
            a1 += xv[k] * wr[k + 2304];
            a2 += xv[k] * wr[k + 4608];
            a3 += xv[k] * wr[k + 6912];
        }
    }
    h64[(o0+0)*NPIX + p] = a0;
    h64[(o0+1)*NPIX + p] = a1;
    h64[(o0+2)*NPIX + p] = a2;
    h64[(o0+3)*NPIX + p] = a3;
}

// ---------------------------------------------------------------- 1x1 convs (reg 36 + cls 18)
__global__ __launch_bounds__(256) void k_conv1(const double* __restrict__ h64,
                                               const float* __restrict__ regw,
                                               const float* __restrict__ regb,
                                               const float* __restrict__ clsw,
                                               const float* __restrict__ clsb,
                                               float* __restrict__ out,
                                               double* __restrict__ reg64,
                                               double* __restrict__ score64) {
    int oc = blockIdx.y;                       // 0..53
    int p  = blockIdx.x * 256 + threadIdx.x;
    if (p >= NPIX) return;
    const float* wr; double bias;
    if (oc < 36) { wr = regw + oc * 256;      bias = (double)regb[oc]; }
    else         { wr = clsw + (oc-36) * 256; bias = (double)clsb[oc-36]; }
    double acc = bias;
    #pragma unroll 8
    for (int ci = 0; ci < 256; ++ci)
        acc += h64[ci * NPIX + p] * (double)wr[ci];
    float v = (float)acc;
    if (oc < 36) {
        out[LOCS_OFF + p*36 + oc] = v;
        reg64[p*36 + oc] = acc;                // == reg64[4*t + j], t = p*9+a
    } else {
        int c = oc - 36;
        out[CLS_OFF  + p*18 + c] = v;
        out[CLS2_OFF + p*18 + c] = v;
        if (c & 1) {
            out[OBJ_OFF + p*9 + (c >> 1)] = v;
            score64[p*9 + (c >> 1)] = acc;
        }
    }
}

// ---------------------------------------------------------------- decode + sort keys
__global__ __launch_bounds__(256) void k_decode(const double* __restrict__ reg64,
                                                const double* __restrict__ score64,
                                                double* __restrict__ roi64,
                                                u64* __restrict__ keys) {
    int t = blockIdx.x * 256 + threadIdx.x;    // grid 128 -> 32768
    if (t >= NANC) { keys[t] = ~0ull; return; }
    int pos = t / 9, a = t % 9;
    int py = pos / FEAT, px = pos % FEAT;
    int ri = a / 3, si = a % 3;
    double rat = (ri == 0) ? 0.5 : (ri == 1 ? 1.0 : 2.0);
    double scl = (si == 0) ? 4.0 : (si == 1 ? 8.0 : 16.0);
    double hA = 4.0 * scl * sqrt(rat);
    double wA = 4.0 * scl * sqrt(1.0 / rat);
    double cy0 = 4.0 * py + 2.0, cx0 = 4.0 * px + 2.0;
    // anchors go through f32 exactly like make_anchors().astype(float32)
    float y1f = (float)(cy0 - hA / 2.0), x1f = (float)(cx0 - wA / 2.0);
    float y2f = (float)(cy0 + hA / 2.0), x2f = (float)(cx0 + wA / 2.0);
    double ah = (double)y2f - (double)y1f, aw = (double)x2f - (double)x1f;
    double acy = (double)y1f + 0.5 * ah, acx = (double)x1f + 0.5 * aw;
    double l0 = reg64[4*t+0], l1 = reg64[4*t+1], l2 = reg64[4*t+2], l3 = reg64[4*t+3];
    double cy = l0 * ah + acy, cx = l1 * aw + acx;
    double hh = exp(l2) * ah,  ww = exp(l3) * aw;
    double r0 = fmin(fmax(cy - 0.5*hh, 0.0), 210.0);
    double r1 = fmin(fmax(cx - 0.5*ww, 0.0), 210.0);
    double r2 = fmin(fmax(cy + 0.5*hh, 0.0), 210.0);
    double r3 = fmin(fmax(cx + 0.5*ww, 0.0), 210.0);
    roi64[4*t+0] = r0; roi64[4*t+1] = r1; roi64[4*t+2] = r2; roi64[4*t+3] = r3;
    bool valid = (r2 - r0 >= 16.0) && (r3 - r1 >= 16.0);
    double m = valid ? score64[t] : -__builtin_huge_val();
    long long ll = __double_as_longlong(m);
    u64 u = (u64)ll;
    u64 mono = (ll < 0) ? ~u : (u ^ 0x8000000000000000ull); // ascending numeric
    keys[t] = ((~mono) & 0xFFFFFFFFFFFF0000ull) | (u64)t;   // asc key = desc score, stable
}

// ---------------------------------------------------------------- bitonic sort pieces
__global__ __launch_bounds__(1024) void k_sortA(u64* __restrict__ keys) {
    __shared__ u64 s[8192];                    // 64 KiB
    const int base = blockIdx.x * 8192;
    for (int t = threadIdx.x; t < 8192; t += 1024) s[t] = keys[base + t];
    __syncthreads();
    for (int k = 2; k <= 8192; k <<= 1) {
        for (int j = k >> 1; j > 0; j >>= 1) {
            for (int q = threadIdx.x; q < 4096; q += 1024) {
                int i = ((q & ~(j-1)) << 1) | (q & (j-1));
                int l = i | j;
                bool asc = (((base + i) & k) == 0);
                u64 A = s[i], B = s[l];
                bool sw = asc ? (A > B) : (A < B);
                if (sw) { s[i] = B; s[l] = A; }
            }
            __syncthreads();
        }
    }
    for (int t = threadIdx.x; t < 8192; t += 1024) keys[base + t] = s[t];
}

__global__ __launch_bounds__(1024) void k_sortB(u64* __restrict__ keys, int k) {
    __shared__ u64 s[8192];
    const int base = blockIdx.x * 8192;
    for (int t = threadIdx.x; t < 8192; t += 1024) s[t] = keys[base + t];
    __syncthreads();
    for (int j = 4096; j > 0; j >>= 1) {
        for (int q = threadIdx.x; q < 4096; q += 1024) {
            int i = ((q & ~(j-1)) << 1) | (q & (j-1));
            int l = i | j;
            bool asc = (((base + i) & k) == 0);
            u64 A = s[i], B = s[l];
            bool sw = asc ? (A > B) : (A < B);
            if (sw) { s[i] = B; s[l] = A; }
        }
        __syncthreads();
    }
    for (int t = threadIdx.x; t < 8192; t += 1024) keys[base + t] = s[t];
}

__global__ __launch_bounds__(256) void k_sortG(u64* __restrict__ keys, int k, int j) {
    int t = blockIdx.x * 256 + threadIdx.x;    // 16384 pairs
    int i = ((t & ~(j-1)) << 1) | (t & (j-1));
    int l = i | j;
    bool asc = ((i & k) == 0);
    u64 A = keys[i], B = keys[l];
    bool sw = asc ? (A > B) : (A < B);
    if (sw) { keys[i] = B; keys[l] = A; }
}

// ---------------------------------------------------------------- gather top-12000
__global__ __launch_bounds__(256) void k_gather(const u64* __restrict__ keys,
                                                const double* __restrict__ roi64,
                                                double* __restrict__ sbox,
                                                double* __restrict__ sarea,
                                                u64* __restrict__ suppinit) {
    int p = blockIdx.x * 256 + threadIdx.x;    // grid 48 -> 12288
    bool sup = true;
    if (p < PRE) {
        int idx = (int)(keys[p] & 0xFFFFull);
        double b0 = roi64[4*idx+0], b1 = roi64[4*idx+1];
        double b2 = roi64[4*idx+2], b3 = roi64[4*idx+3];
        sbox[4*p+0] = b0; sbox[4*p+1] = b1; sbox[4*p+2] = b2; sbox[4*p+3] = b3;
        sarea[p] = (b3 - b1 + 1.0) * (b2 - b0 + 1.0);
        sup = !((b2 - b0 >= 16.0) && (b3 - b1 >= 16.0));
    } else {
        sbox[4*p+0] = 0.0; sbox[4*p+1] = 0.0; sbox[4*p+2] = 0.0; sbox[4*p+3] = 0.0;
        sarea[p] = 1.0;
    }
    u64 ball = __ballot(sup);
    if ((threadIdx.x & 63) == 0) suppinit[p >> 6] = ball;
}

// ---------------------------------------------------------------- suppression bit matrix
__global__ __launch_bounds__(256) void k_mask(const double* __restrict__ sbox,
                                              const double* __restrict__ sarea,
                                              u64* __restrict__ mask) {
    const int jt = blockIdx.x, it = blockIdx.y;     // (12, 188)
    const int ib = it * 64, jb0 = jt * 1024;
    if (jb0 + 1023 <= ib) {                         // whole tile has j <= i -> zeros
        for (int t = threadIdx.x; t < 1024; t += 256) {
            int ti = t >> 4, w = t & 15;
            int i = ib + ti;
            if (i < PRE) mask[(size_t)i * ROWW + jt*16 + w] = 0ull;
        }
        return;
    }
    __shared__ double jbx[4096];
    __shared__ double jar[1024];
    for (int t = threadIdx.x; t < 4096; t += 256) jbx[t] = sbox[(size_t)jb0*4 + t];
    for (int t = threadIdx.x; t < 1024; t += 256) jar[t] = sarea[jb0 + t];
    __syncthreads();
    int ti = threadIdx.x >> 2;
    int i = ib + ti;
    if (i >= PRE) return;
    double iy1 = sbox[4*i+0], ix1 = sbox[4*i+1], iy2 = sbox[4*i+2], ix2 = sbox[4*i+3];
    double iar = sarea[i];
    for (int w = (threadIdx.x & 3); w < 16; w += 4) {
        u64 bits = 0ull;
        int q0 = w * 64;
        for (int l = 0; l < 64; ++l) {
            int q = q0 + l;
            double jy1 = jbx[4*q+0], jx1 = jbx[4*q+1], jy2 = jbx[4*q+2], jx2 = jbx[4*q+3];
            double yy1 = fmax(iy1, jy1), xx1 = fmax(ix1, jx1);
            double yy2 = fmin(iy2, jy2), xx2 = fmin(ix2, jx2);
            double iw = fmax(xx2 - xx1 + 1.0, 0.0);
            double ih = fmax(yy2 - yy1 + 1.0, 0.0);
            double inter = iw * ih;
            bool s = ((jb0 + q) > i) && (inter > 0.7 * (iar + jar[q] - inter));
            bits |= ((u64)s) << l;
        }
        mask[(size_t)i * ROWW + jt*16 + w] = bits;
    }
}

// ---------------------------------------------------------------- sequential chunked NMS scan
__global__ __launch_bounds__(1024) void k_scan(const u64* __restrict__ mask,
                                               const u64* __restrict__ suppinit,
                                               const double* __restrict__ sbox,
                                               float* __restrict__ rois) {
    __shared__ u64 diag[4096];        // 512 rows x 8 words
    __shared__ u64 supp[192];
    __shared__ u32 keptIdx[POST];
    __shared__ int chunkKept[512];
    __shared__ int kcS, rankS, doneS;
    const int tid = threadIdx.x;
    if (tid < 192) supp[tid] = suppinit[tid];
    if (tid == 0) { rankS = 0; doneS = 0; }
    __syncthreads();
    for (int c = 0; c < 24; ++c) {
        for (int t = tid; t < 4096; t += 1024) {
            int r = t >> 3, w = t & 7;
            int i = c * 512 + r;
            diag[t] = (i < PRE) ? mask[(size_t)i * ROWW + c*8 + w] : 0ull;
        }
        if (tid == 0) kcS = 0;
        __syncthreads();
        if (tid < 64) {                 // wave 0: serial in-chunk resolution
            u64 st0 = supp[c*8+0], st1 = supp[c*8+1], st2 = supp[c*8+2], st3 = supp[c*8+3];
            u64 st4 = supp[c*8+4], st5 = supp[c*8+5], st6 = supp[c*8+6], st7 = supp[c*8+7];
            int rk = rankS, kcl = 0;
            bool done2 = false;
#define SCAN_WORD(W)                                                            \
            if (!done2) {                                                       \
                u64 cur = st##W;                                                \
                while (cur != ~0ull) {                                          \
                    int bpos = __builtin_ctzll(~cur);                           \
                    int lbit = W*64 + bpos;                                     \
                    if (tid == 0) { keptIdx[rk] = (u32)(c*512 + lbit);          \
                                    chunkKept[kcl] = lbit; }                    \
                    rk++; kcl++;                                                \
                    if (rk >= POST) { done2 = true; break; }                    \
                    const u64* dr = diag + lbit*8;                              \
                    u64 q0=dr[0],q1=dr[1],q2=dr[2],q3=dr[3];                    \
                    u64 q4=dr[4],q5=dr[5],q6=dr[6],q7=dr[7];                    \
                    st0|=q0; st1|=q1; st2|=q2; st3|=q3;                         \
                    st4|=q4; st5|=q5; st6|=q6; st7|=q7;                         \
                    cur = cur | (1ull << bpos) | q##W;                          \
                }                                                               \
            }
            SCAN_WORD(0) SCAN_WORD(1) SCAN_WORD(2) SCAN_WORD(3)
            SCAN_WORD(4) SCAN_WORD(5) SCAN_WORD(6) SCAN_WORD(7)
#undef SCAN_WORD
            if (tid == 0) { rankS = rk; kcS = kcl; if (done2) doneS = 1; }
        }
        __syncthreads();
        int kcount = kcS;
        bool done = (doneS != 0);
        if (!done && kcount > 0) {      // parallel cross-chunk suppression
            int w0 = (c + 1) * 8;
            for (int gw = w0 + tid; gw < ROWW; gw += 1024) {
                u64 acc = supp[gw];
                #pragma unroll 4
                for (int k = 0; k < kcount; ++k) {
                    int p = c*512 + chunkKept[k];
                    acc |= mask[(size_t)p * ROWW + gw];
                }
                supp[gw] = acc;
            }
        }
        __syncthreads();
        if (done) break;
    }
    int R = rankS;
    for (int r = tid; r < POST; r += 1024) {
        if (r < R) {
            int p = (int)keptIdx[r];
            rois[4*r+0] = (float)sbox[4*p+0];
            rois[4*r+1] = (float)sbox[4*p+1];
            rois[4*r+2] = (float)sbox[4*p+2];
            rois[4*r+3] = (float)sbox[4*p+3];
        } // else stays zero (memset)
    }
}

// ---------------------------------------------------------------- launcher
extern "C" void kernel_launch(void* const* d_in, const int* in_sizes, int n_in,
                              void* d_out, int out_size, void* d_ws, size_t ws_size,
                              hipStream_t stream) {
    const float* x    = (const float*)d_in[0];
    const float* w1   = (const float*)d_in[1];
    const float* b1   = (const float*)d_in[2];
    const float* regw = (const float*)d_in[3];
    const float* regb = (const float*)d_in[4];
    const float* clsw = (const float*)d_in[5];
    const float* clsb = (const float*)d_in[6];
    float* out = (float*)d_out;

    char* ws = (char*)d_ws;
    double* x64    = (double*)(ws + OFF_X64);
    double* h64    = (double*)(ws + OFF_H64);
    double* reg64  = (double*)(ws + OFF_REG64);
    double* sc64   = (double*)(ws + OFF_SC64);
    double* roi64  = (double*)(ws + OFF_ROI64);
    u64*    keys   = (u64*)   (ws + OFF_KEYS);
    double* sbox   = (double*)(ws + OFF_SBOX);
    double* sarea  = (double*)(ws + OFF_SAREA);
    u64*    supp0  = (u64*)   (ws + OFF_SUPP);
    u64*    maskp  = (u64*)   (ws + OFF_MASK);

    hipMemsetAsync(d_out, 0, 8000 * sizeof(float), stream);  // rois zero-padding

    k_prep <<<2704, 256, 0, stream>>>(x, x64);
    k_conv3<<<dim3(11, 64), 256, 0, stream>>>(x64, w1, b1, h64);
    k_conv1<<<dim3(11, 54), 256, 0, stream>>>(h64, regw, regb, clsw, clsb, out, reg64, sc64);
    k_decode<<<128, 256, 0, stream>>>(reg64, sc64, roi64, keys);

    k_sortA<<<4, 1024, 0, stream>>>(keys);
    k_sortG<<<64, 256, 0, stream>>>(keys, 16384, 8192);
    k_sortB<<<4, 1024, 0, stream>>>(keys, 16384);
    k_sortG<<<64, 256, 0, stream>>>(keys, 32768, 16384);
    k_sortG<<<64, 256, 0, stream>>>(keys, 32768, 8192);
    k_sortB<<<4, 1024, 0, stream>>>(keys, 32768);

    k_gather<<<48, 256, 0, stream>>>(keys, roi64, sbox, sarea, supp0);
    k_mask<<<dim3(12, 188), 256, 0, stream>>>(sbox, sarea, maskp);
    k_scan<<<1, 1024, 0, stream>>>(maskp, supp0, sbox, out + ROIS_OFF);
}